// Round 5
// baseline (1189.372 us; speedup 1.0000x reference)
//
#include <hip/hip_runtime.h>
#include <hip/hip_cooperative_groups.h>

namespace cg = cooperative_groups;

// ChemResBlock: A=2048 atoms, D=64 depth, F=12 taps.
// out[a,o] = sum_{n,f} conn[a][n*12+f] * Gt[o][n*12+f] + bterm[a,o]
// R11: DISPATCH-COLLAPSE EXPERIMENT. R3/R4 probes proved all kernels sum to
// ~160-190us while wall time is ~456us -> ~270us is inter-dispatch overhead.
// This round: k_prep+k_cvt merged (independent roles, 1 dispatch); the 12
// per-layer dispatches replaced by ONE cooperative kernel (512 blocks = 2/CU
// co-resident at 72KB LDS) with 11 grid.sync()s. Phase bodies are ports of
// the R4-validated kernels. Fallback to separate dispatches if cooperative
// launch is unavailable/fails.

#define A_N 2048
#define D_N 64
#define F_N 12
#define K_TOTAL (A_N * F_N)        // 24576
#define NSPLIT 32
#define KSEG (K_TOTAL / NSPLIT)    // 768
#define BK 64
#define NKB (KSEG / BK)            // 12

typedef short short8 __attribute__((ext_vector_type(8)));
typedef float f32x16 __attribute__((ext_vector_type(16)));

#define GLOAD16(ldsp, gp)                                                        \
  __builtin_amdgcn_global_load_lds(                                              \
      (const __attribute__((address_space(1))) void*)(gp),                       \
      (__attribute__((address_space(3))) void*)(ldsp), 16, 0, 0)

#define VMWAIT(n) asm volatile("s_waitcnt vmcnt(" #n ")" ::: "memory")

// pack two floats to bf16 pair with round-to-nearest-even
__device__ __forceinline__ unsigned pk_bf16(float a, float b) {
  unsigned ua = __float_as_uint(a);
  unsigned ub = __float_as_uint(b);
  ua += 0x7fffu + ((ua >> 16) & 1u);
  ub += 0x7fffu + ((ub >> 16) & 1u);
  return (ua >> 16) | (ub & 0xffff0000u);
}

__device__ __forceinline__ unsigned short bf16_1(float v) {
  unsigned u = __float_as_uint(v);
  u += 0x7fffu + ((u >> 16) & 1u);
  return (unsigned short)(u >> 16);
}

// ---------------- k_pre: x transpose + bterm + conn->bf16 tiled convert ----------------
// blocks 0..31: xt transpose; 32..543: bterm; 544..6687: cvt (6144 tiles).
// All roles independent (no ordering needed within the dispatch).
__global__ void k_pre(const float* __restrict__ x, float* __restrict__ xt,
                      const float* __restrict__ bond, const float* __restrict__ f0,
                      const float* __restrict__ f1, float* __restrict__ bt0,
                      float* __restrict__ bt1, const float* __restrict__ conn,
                      unsigned short* __restrict__ connt) {
  int t = threadIdx.x, b = blockIdx.x;
  if (b < 32) {
    __shared__ float ld[64][65];
    int m0 = b * 64;
    int r = t >> 2, cq = (t & 3) * 16;
    const float4* src = (const float4*)(x + (size_t)(m0 + r) * 64 + cq);
#pragma unroll
    for (int i = 0; i < 4; ++i) {
      float4 v = src[i];
      ld[r][cq + i * 4 + 0] = v.x;
      ld[r][cq + i * 4 + 1] = v.y;
      ld[r][cq + i * 4 + 2] = v.z;
      ld[r][cq + i * 4 + 3] = v.w;
    }
    __syncthreads();
    int c = t >> 2, ml0 = (t & 3) * 16;
    float4* dst = (float4*)(xt + (size_t)c * 2048 + m0 + ml0);
#pragma unroll
    for (int i = 0; i < 4; ++i) {
      float4 v;
      v.x = ld[ml0 + i * 4 + 0][c];
      v.y = ld[ml0 + i * 4 + 1][c];
      v.z = ld[ml0 + i * 4 + 2][c];
      v.w = ld[ml0 + i * 4 + 3][c];
      dst[i] = v;
    }
  } else if (b < 544) {
    int b2 = b - 32;                   // 0..511
    int a = (b2 & 31) * 64 + (t & 63);
    int o = (b2 >> 5) * 4 + (t >> 6);
    float s0 = 0.f, s1 = 0.f;
#pragma unroll
    for (int f = 0; f < F_N; ++f) {
#pragma unroll
      for (int j = 0; j < 2; ++j) {
        float bv = bond[a * 24 + f * 2 + j];
        s0 += bv * f0[o * 792 + f * 66 + 64 + j];
        s1 += bv * f1[o * 792 + f * 66 + 64 + j];
      }
    }
    bt0[o * 2048 + a] = s0;
    bt1[o * 2048 + a] = s1;
  } else {
    int i = b - 544;                   // 0..6143: tile (atile, ks, kb)
    int atile = i / 384;
    int r2 = i % 384;
    int ks = r2 / 12, kb = r2 % 12;
    const float* src = conn + (size_t)(atile * 128) * K_TOTAL + ks * KSEG + kb * 64;
    unsigned short* dst = connt + (size_t)((atile * NSPLIT + ks) * NKB + kb) * 8192;
    int r0 = t >> 3, c0 = (t & 7) * 8;
#pragma unroll
    for (int q = 0; q < 4; ++q) {
      int row = r0 + q * 32;
      const float4* s4 = (const float4*)(src + (size_t)row * K_TOTAL + c0);
      float4 a = s4[0], bb = s4[1];
      uint4 p;
      p.x = pk_bf16(a.x, a.y);
      p.y = pk_bf16(a.z, a.w);
      p.z = pk_bf16(bb.x, bb.y);
      p.w = pk_bf16(bb.z, bb.w);
      *(uint4*)(dst + row * 64 + c0) = p;
    }
  }
}

// ---------------- phase G: Gt -> tiled gtt[q][o][c]  (512 blocks: o=bid>>3, bx=bid&7) ----------------
__device__ __forceinline__ void phase_g(unsigned short* smem, int bid, int t,
                                        const float* __restrict__ vin,
                                        const float* __restrict__ filt,
                                        unsigned short* __restrict__ gtt) {
  float* WT = (float*)smem;                 // [64][12] floats, 3 KB at offset 0
  unsigned short* sg = smem + 8192;         // 3072 shorts (6 KB) at byte 16384
  int o = bid >> 3, bx = bid & 7;
  for (int i = t; i < 768; i += 256) {
    int d = i / 12, f = i % 12;
    WT[d * 12 + f] = filt[o * 792 + f * 66 + d];
  }
  __syncthreads();
  int n0 = bx * 256 + t;
  float acc[12];
#pragma unroll
  for (int f = 0; f < 12; ++f) acc[f] = 0.f;
#pragma unroll 4
  for (int d = 0; d < 64; ++d) {
    float v = vin[d * 2048 + n0];
    const float4* wp = (const float4*)(WT + d * 12);
    float4 w0 = wp[0], w1 = wp[1], w2 = wp[2];
    acc[0] += v * w0.x;  acc[1] += v * w0.y;  acc[2]  += v * w0.z;  acc[3]  += v * w0.w;
    acc[4] += v * w1.x;  acc[5] += v * w1.y;  acc[6]  += v * w1.z;  acc[7]  += v * w1.w;
    acc[8] += v * w2.x;  acc[9] += v * w2.y;  acc[10] += v * w2.z;  acc[11] += v * w2.w;
  }
#pragma unroll
  for (int f = 0; f < 12; ++f) sg[t * 12 + f] = bf16_1(acc[f]);
  __syncthreads();
  // local k = t*12+f; global k = bx*3072 + lk -> q = bx*48 + (lk>>6), c = lk&63.
  // 384 dense 16B chunks: chunk m covers lk [m*8, m*8+8).
  unsigned short* gbase = gtt + (size_t)(bx * 48) * 4096 + o * 64;
#pragma unroll
  for (int j = 0; j < 2; ++j) {
    int m = t + j * 256;
    if (m < 384)
      *(uint4*)(gbase + (size_t)(m >> 3) * 4096 + (m & 7) * 8) = *(const uint4*)(sg + m * 8);
  }
}

// ---------------- phase BIG: split-K GEMM, 3-buffer counted-vmcnt pipeline ----------------
// bid -> atile = bid&15, ks = bid>>4.  (Identical body to R4-validated k_big.)
__device__ __forceinline__ void phase_big(unsigned short* smem, int bid, int t,
                                          const unsigned short* __restrict__ connt,
                                          const unsigned short* __restrict__ gtt,
                                          float* __restrict__ part) {
  int lane = t & 63, w = t >> 6;
  int atile = bid & 15, ks = bid >> 4;
  const unsigned short* ct = connt + (size_t)(atile * NSPLIT + ks) * (NKB * 8192);
  const unsigned short* gs = gtt + (size_t)ks * (NKB * 4096);

  int rl = lane >> 3, sl = lane & 7;
  int cs = sl ^ rl;

  int cSrc[4], gSrc[2], cDst[4], gDst[2];
#pragma unroll
  for (int j = 0; j < 4; ++j) {
    cSrc[j] = (w * 32 + j * 8 + rl) * 64 + cs * 8;
    cDst[j] = (w * 32 + j * 8) * 64;          // wave-uniform LDS base (glds appends lane*16B)
  }
#pragma unroll
  for (int j = 0; j < 2; ++j) {
    gSrc[j] = (w * 16 + j * 8 + rl) * 64 + cs * 8;
    gDst[j] = 8192 + (w * 16 + j * 8) * 64;
  }

  f32x16 acc0, acc1;
#pragma unroll
  for (int i = 0; i < 16; ++i) { acc0[i] = 0.f; acc1[i] = 0.f; }

  int oh = w >> 1, ah = w & 1;
  int orow = oh * 32 + (lane & 31);
  int arow = ah * 64 + (lane & 31);
  int sw = lane & 7;
  int khalf = lane >> 5;

  VMWAIT(0);  // clean vmcnt baseline for the counted waits below

  // prologue: prefetch tiles 0,1 (12 vm-ops/wave outstanding)
#pragma unroll
  for (int p = 0; p < 2; ++p) {
    unsigned short* base = smem + p * 12288;
#pragma unroll
    for (int j = 0; j < 4; ++j) GLOAD16(base + cDst[j], ct + p * 8192 + cSrc[j]);
#pragma unroll
    for (int j = 0; j < 2; ++j) GLOAD16(base + gDst[j], gs + p * 4096 + gSrc[j]);
  }

#pragma unroll
  for (int kb = 0; kb < NKB; ++kb) {
    // outstanding here: tiles kb (6) + kb+1 (6). vmcnt(6) => tile kb landed.
    if (kb < NKB - 1) VMWAIT(6);
    else VMWAIT(0);
    __builtin_amdgcn_s_barrier();          // collective visibility of tile kb
    asm volatile("" ::: "memory");         // keep LDS reads below the barrier
    if (kb + 2 < NKB) {                    // issue tile kb+2 into buf (kb-1)%3 (reads done)
      unsigned short* base = smem + ((kb + 2) % 3) * 12288;
#pragma unroll
      for (int j = 0; j < 4; ++j) GLOAD16(base + cDst[j], ct + (kb + 2) * 8192 + cSrc[j]);
#pragma unroll
      for (int j = 0; j < 2; ++j) GLOAD16(base + gDst[j], gs + (kb + 2) * 4096 + gSrc[j]);
    }
    const unsigned short* cb = smem + (kb % 3) * 12288;
    const unsigned short* gb = cb + 8192;
#pragma unroll
    for (int kk = 0; kk < 4; ++kk) {
      int c = kk * 2 + khalf;
      int coff = ((c ^ sw) << 3);
      short8 af = *(const short8*)(gb + orow * 64 + coff);
      short8 b0 = *(const short8*)(cb + arow * 64 + coff);
      short8 b1 = *(const short8*)(cb + (arow + 32) * 64 + coff);
      acc0 = __builtin_amdgcn_mfma_f32_32x32x16_bf16(af, b0, acc0, 0, 0, 0);
      acc1 = __builtin_amdgcn_mfma_f32_32x32x16_bf16(af, b1, acc1, 0, 0, 0);
    }
  }

  float* pp = part + (size_t)ks * (64 * 2048);
  int a0 = atile * 128 + ah * 64 + (lane & 31);
  int ob = oh * 32 + 4 * khalf;
#pragma unroll
  for (int rg = 0; rg < 16; ++rg) {
    int o = ob + (rg & 3) + 8 * (rg >> 2);
    pp[o * 2048 + a0] = acc0[rg];
    pp[o * 2048 + a0 + 32] = acc1[rg];
  }
}

// ---------------- phase RED: sum partials + bterm (+x) + relu ----------------
// 512 blocks; thread quarter q sums splits [q*8,q*8+8); quarters combined in LDS.
__device__ __forceinline__ void phase_red(unsigned short* smem, int bid, int t,
                                          const float* __restrict__ part,
                                          const float* __restrict__ bt,
                                          const float* __restrict__ xt,
                                          float* __restrict__ curt,
                                          float* __restrict__ outp,
                                          int residual, int final_layer) {
  float4* rbuf = (float4*)smem;             // 192 float4 = 3 KB
  int i4 = bid * 64 + (t & 63);             // float4 index, 0..32767; layout [o][m]
  int quar = t >> 6;
  int sbase = quar * 8;
  float4 s = {0.f, 0.f, 0.f, 0.f};
#pragma unroll
  for (int k = 0; k < 8; ++k) {
    float4 p = ((const float4*)part)[(size_t)(sbase + k) * 32768 + i4];
    s.x += p.x; s.y += p.y; s.z += p.z; s.w += p.w;
  }
  if (quar) rbuf[(quar - 1) * 64 + (t & 63)] = s;
  __syncthreads();
  if (!quar) {                              // t in [0,64)
    float4 a = rbuf[t], b2 = rbuf[64 + t], c2 = rbuf[128 + t];
    float4 b = ((const float4*)bt)[i4];
    s.x += a.x + b2.x + c2.x + b.x;
    s.y += a.y + b2.y + c2.y + b.y;
    s.z += a.z + b2.z + c2.z + b.z;
    s.w += a.w + b2.w + c2.w + b.w;
    if (residual) {
      float4 rr = ((const float4*)xt)[i4];
      s.x += rr.x; s.y += rr.y; s.z += rr.z; s.w += rr.w;
    }
    s.x = fmaxf(s.x, 0.f); s.y = fmaxf(s.y, 0.f);
    s.z = fmaxf(s.z, 0.f); s.w = fmaxf(s.w, 0.f);
    ((float4*)curt)[i4] = s;
    if (final_layer) {
      int idx = i4 * 4;
      int o = idx >> 11, m = idx & 2047;
      outp[(m + 0) * 64 + o] = s.x;
      outp[(m + 1) * 64 + o] = s.y;
      outp[(m + 2) * 64 + o] = s.z;
      outp[(m + 3) * 64 + o] = s.w;
    }
  }
}

// ---------------- cooperative mega-kernel: 4 layers, 11 grid syncs ----------------
__launch_bounds__(256, 2)
__global__ void k_mega(const unsigned short* __restrict__ connt,
                       const float* __restrict__ f0, const float* __restrict__ f1,
                       const float* __restrict__ xt, const float* __restrict__ bt0,
                       const float* __restrict__ bt1, unsigned short* __restrict__ gtt,
                       float* __restrict__ part, float* __restrict__ curt,
                       float* __restrict__ outp) {
  cg::grid_group grid = cg::this_grid();
  __shared__ __align__(16) unsigned short smem[36864];  // 72 KB -> 2 blocks/CU
  int t = threadIdx.x, bid = blockIdx.x;
#pragma unroll 1
  for (int layer = 0; layer < 4; ++layer) {
    const float* filt = (layer < 2) ? f0 : f1;
    const float* bt   = (layer < 2) ? bt0 : bt1;
    const float* vin  = (layer == 0) ? xt : curt;
    phase_g(smem, bid, t, vin, filt, gtt);
    grid.sync();
    phase_big(smem, bid, t, connt, gtt, part);
    grid.sync();
    phase_red(smem, bid, t, part, bt, xt, curt, outp, layer & 1, layer == 3);
    if (layer < 3) grid.sync();
  }
}

// ---------------- fallback standalone kernels (same phase bodies) ----------------
__global__ void k_g_f(const float* __restrict__ vin, const float* __restrict__ filt,
                      unsigned short* __restrict__ gtt) {
  __shared__ __align__(16) unsigned short smem[11264];  // WT@0 (3KB) + sg@16KB (6KB)
  phase_g(smem, blockIdx.x, threadIdx.x, vin, filt, gtt);
}

__launch_bounds__(256, 2)
__global__ void k_big_f(const unsigned short* __restrict__ connt,
                        const unsigned short* __restrict__ gtt,
                        float* __restrict__ part) {
  __shared__ __align__(16) unsigned short smem[36864];
  phase_big(smem, blockIdx.x, threadIdx.x, connt, gtt, part);
}

__global__ void k_red_f(const float* __restrict__ part, const float* __restrict__ bt,
                        const float* __restrict__ xt, float* __restrict__ curt,
                        float* __restrict__ outp, int residual, int final_layer) {
  __shared__ __align__(16) unsigned short smem[1536];   // 3 KB rbuf
  phase_red(smem, blockIdx.x, threadIdx.x, part, bt, xt, curt, outp, residual, final_layer);
}

extern "C" void kernel_launch(void* const* d_in, const int* in_sizes, int n_in,
                              void* d_out, int out_size, void* d_ws, size_t ws_size,
                              hipStream_t stream) {
  const float* x    = (const float*)d_in[0];  // (2048, 64)
  const float* conn = (const float*)d_in[1];  // (2048, 2048, 12)
  const float* bond = (const float*)d_in[2];  // (2048, 12, 2)
  const float* f0   = (const float*)d_in[3];  // (64, 12, 66)
  const float* f1   = (const float*)d_in[4];
  float* out = (float*)d_out;                 // (2048, 64)

  char* ws = (char*)d_ws;
  float* xt   = (float*)(ws + 0);              // 64x2048 fp32            512 KB
  float* curt = (float*)(ws + 524288);         // 64x2048 fp32            512 KB
  float* bt0  = (float*)(ws + 1048576);        // 64x2048 fp32            512 KB
  float* bt1  = (float*)(ws + 1572864);        // 64x2048 fp32            512 KB
  unsigned short* gtt = (unsigned short*)(ws + 2097152);     // tiled gt    3 MB
  float* part = (float*)(ws + 5242880);        // 32 x 64x2048 fp32       16 MB
  unsigned short* connt = (unsigned short*)(ws + 33554432);  // tiled conn  96 MB

  k_pre<<<6688, 256, 0, stream>>>(x, xt, bond, f0, f1, bt0, bt1, conn, connt);

  static int coop = -1;
  if (coop < 0) {
    int dev = 0, v = 0;
    if (hipGetDevice(&dev) == hipSuccess &&
        hipDeviceGetAttribute(&v, hipDeviceAttributeCooperativeLaunch, dev) == hipSuccess)
      coop = v ? 1 : 0;
    else
      coop = 0;
  }

  bool done = false;
  if (coop) {
    const unsigned short* a_connt = connt;
    const float *a_f0 = f0, *a_f1 = f1, *a_xt = xt, *a_bt0 = bt0, *a_bt1 = bt1;
    unsigned short* a_gtt = gtt;
    float *a_part = part, *a_curt = curt, *a_out = out;
    void* args[10] = {&a_connt, &a_f0, &a_f1, &a_xt, &a_bt0,
                      &a_bt1, &a_gtt, &a_part, &a_curt, &a_out};
    hipError_t e = hipLaunchCooperativeKernel((const void*)k_mega, dim3(512), dim3(256),
                                              args, 0, stream);
    if (e == hipSuccess) done = true;
  }

  if (!done) {
    for (int layer = 0; layer < 4; ++layer) {
      const float* filt = (layer < 2) ? f0 : f1;
      const float* bt   = (layer < 2) ? bt0 : bt1;
      const float* vin  = (layer == 0) ? xt : curt;
      k_g_f<<<512, 256, 0, stream>>>(vin, filt, gtt);
      k_big_f<<<512, 256, 0, stream>>>(connt, gtt, part);
      k_red_f<<<512, 256, 0, stream>>>(part, bt, xt, curt, out, layer & 1, layer == 3);
    }
  }
}

// Round 6
// 548.703 us; speedup vs baseline: 2.1676x; 2.1676x over previous
//
#include <hip/hip_runtime.h>

// ChemResBlock: A=2048 atoms, D=64 depth, F=12 taps.
// out[a,o] = sum_{n,f} conn[a][n*12+f] * Gt[o][n*12+f] + bterm[a,o]
// R12: R5 post-mortem: grid.sync ~65us each on MI355X (k_mega 890us) -- coop
// REVERTED. Boundary-count reduction via plain fusion instead:
//   k_rg = k_reduce(L) + k_g(L+1) fused: block (ks,oq) sums part over 32
//   splits for its 64 atoms, bias/residual/relu in-register, computes the
//   Gt tile directly (W via wave-uniform scalar loads, no curt round-trip).
//   Schedule: pre -> (rg -> big)x4 -> redF = 10 dispatches (was 14).
// k_big is the R3-measured body (21.7us/pass), k_pre/k_red are R5-validated.

#define A_N 2048
#define D_N 64
#define F_N 12
#define K_TOTAL (A_N * F_N)        // 24576
#define NSPLIT 32
#define KSEG (K_TOTAL / NSPLIT)    // 768
#define BK 64
#define NKB (KSEG / BK)            // 12

typedef short short8 __attribute__((ext_vector_type(8)));
typedef float f32x16 __attribute__((ext_vector_type(16)));

#define GLOAD16(ldsp, gp)                                                        \
  __builtin_amdgcn_global_load_lds(                                              \
      (const __attribute__((address_space(1))) void*)(gp),                       \
      (__attribute__((address_space(3))) void*)(ldsp), 16, 0, 0)

#define VMWAIT(n) asm volatile("s_waitcnt vmcnt(" #n ")" ::: "memory")

// pack two floats to bf16 pair with round-to-nearest-even
__device__ __forceinline__ unsigned pk_bf16(float a, float b) {
  unsigned ua = __float_as_uint(a);
  unsigned ub = __float_as_uint(b);
  ua += 0x7fffu + ((ua >> 16) & 1u);
  ub += 0x7fffu + ((ub >> 16) & 1u);
  return (ua >> 16) | (ub & 0xffff0000u);
}

__device__ __forceinline__ unsigned short bf16_1(float v) {
  unsigned u = __float_as_uint(v);
  u += 0x7fffu + ((u >> 16) & 1u);
  return (unsigned short)(u >> 16);
}

// ---------------- k_pre: x transpose + bterm + conn->bf16 tiled convert ----------------
// blocks 0..31: xt transpose; 32..543: bterm; 544..6687: cvt (6144 tiles).
__global__ void k_pre(const float* __restrict__ x, float* __restrict__ xt,
                      const float* __restrict__ bond, const float* __restrict__ f0,
                      const float* __restrict__ f1, float* __restrict__ bt0,
                      float* __restrict__ bt1, const float* __restrict__ conn,
                      unsigned short* __restrict__ connt) {
  int t = threadIdx.x, b = blockIdx.x;
  if (b < 32) {
    __shared__ float ld[64][65];
    int m0 = b * 64;
    int r = t >> 2, cq = (t & 3) * 16;
    const float4* src = (const float4*)(x + (size_t)(m0 + r) * 64 + cq);
#pragma unroll
    for (int i = 0; i < 4; ++i) {
      float4 v = src[i];
      ld[r][cq + i * 4 + 0] = v.x;
      ld[r][cq + i * 4 + 1] = v.y;
      ld[r][cq + i * 4 + 2] = v.z;
      ld[r][cq + i * 4 + 3] = v.w;
    }
    __syncthreads();
    int c = t >> 2, ml0 = (t & 3) * 16;
    float4* dst = (float4*)(xt + (size_t)c * 2048 + m0 + ml0);
#pragma unroll
    for (int i = 0; i < 4; ++i) {
      float4 v;
      v.x = ld[ml0 + i * 4 + 0][c];
      v.y = ld[ml0 + i * 4 + 1][c];
      v.z = ld[ml0 + i * 4 + 2][c];
      v.w = ld[ml0 + i * 4 + 3][c];
      dst[i] = v;
    }
  } else if (b < 544) {
    int b2 = b - 32;                   // 0..511
    int a = (b2 & 31) * 64 + (t & 63);
    int o = (b2 >> 5) * 4 + (t >> 6);
    float s0 = 0.f, s1 = 0.f;
#pragma unroll
    for (int f = 0; f < F_N; ++f) {
#pragma unroll
      for (int j = 0; j < 2; ++j) {
        float bv = bond[a * 24 + f * 2 + j];
        s0 += bv * f0[o * 792 + f * 66 + 64 + j];
        s1 += bv * f1[o * 792 + f * 66 + 64 + j];
      }
    }
    bt0[o * 2048 + a] = s0;
    bt1[o * 2048 + a] = s1;
  } else {
    int i = b - 544;                   // 0..6143: tile (atile, ks, kb)
    int atile = i / 384;
    int r2 = i % 384;
    int ks = r2 / 12, kb = r2 % 12;
    const float* src = conn + (size_t)(atile * 128) * K_TOTAL + ks * KSEG + kb * 64;
    unsigned short* dst = connt + (size_t)((atile * NSPLIT + ks) * NKB + kb) * 8192;
    int r0 = t >> 3, c0 = (t & 7) * 8;
#pragma unroll
    for (int q = 0; q < 4; ++q) {
      int row = r0 + q * 32;
      const float4* s4 = (const float4*)(src + (size_t)row * K_TOTAL + c0);
      float4 a = s4[0], bb = s4[1];
      uint4 p;
      p.x = pk_bf16(a.x, a.y);
      p.y = pk_bf16(a.z, a.w);
      p.z = pk_bf16(bb.x, bb.y);
      p.w = pk_bf16(bb.z, bb.w);
      *(uint4*)(dst + row * 64 + c0) = p;
    }
  }
}

// ---------------- k_rg: fused [reduce(prev layer) -> relu] + [Gt tile compute] ----------------
// grid (4, 32): oq = blockIdx.x (o-quarter, 16 outputs), ks = blockIdx.y (64 atoms).
// mode 0: vin = xt slice (layer 0). mode 1: vin = relu(sum_splits part + bt (+xt)).
// Then gt[k][o] = sum_d vin[a][d]*filt[o][f][d] for k = a*12+f, staged in LDS,
// written as dense 128B segments to gtt[q][o][c] (q = global k>>6, c = k&63).
__global__ void k_rg(const float* __restrict__ part, const float* __restrict__ xt,
                     const float* __restrict__ bt, const float* __restrict__ filt,
                     unsigned short* __restrict__ gtt, int mode, int residual) {
  __shared__ __align__(16) float vin[64][66];          // [atom][d], padded
  __shared__ __align__(16) unsigned short sg[16][768]; // [o_local][local k]
  int t = threadIdx.x;
  int oq = blockIdx.x, ks = blockIdx.y;
  int a0 = ks * 64;

  // ---- phase 1: build vin slice (64 atoms x 64 d) ----
  {
    int d = t >> 2, j4 = (t & 3) * 16;
    float4 s[4];
    if (mode == 0) {
      const float4* xp = (const float4*)(xt + (size_t)d * 2048 + a0 + j4);
#pragma unroll
      for (int i = 0; i < 4; ++i) s[i] = xp[i];
    } else {
#pragma unroll
      for (int i = 0; i < 4; ++i) s[i] = make_float4(0.f, 0.f, 0.f, 0.f);
#pragma unroll 4
      for (int sp = 0; sp < NSPLIT; ++sp) {
        const float4* pp =
            (const float4*)(part + (size_t)sp * 131072 + (size_t)d * 2048 + a0 + j4);
#pragma unroll
        for (int i = 0; i < 4; ++i) {
          float4 p = pp[i];
          s[i].x += p.x; s[i].y += p.y; s[i].z += p.z; s[i].w += p.w;
        }
      }
      const float4* bp = (const float4*)(bt + (size_t)d * 2048 + a0 + j4);
#pragma unroll
      for (int i = 0; i < 4; ++i) {
        float4 p = bp[i];
        s[i].x += p.x; s[i].y += p.y; s[i].z += p.z; s[i].w += p.w;
      }
      if (residual) {
        const float4* xp = (const float4*)(xt + (size_t)d * 2048 + a0 + j4);
#pragma unroll
        for (int i = 0; i < 4; ++i) {
          float4 p = xp[i];
          s[i].x += p.x; s[i].y += p.y; s[i].z += p.z; s[i].w += p.w;
        }
      }
#pragma unroll
      for (int i = 0; i < 4; ++i) {
        s[i].x = fmaxf(s[i].x, 0.f); s[i].y = fmaxf(s[i].y, 0.f);
        s[i].z = fmaxf(s[i].z, 0.f); s[i].w = fmaxf(s[i].w, 0.f);
      }
    }
    const float* sf = (const float*)s;
#pragma unroll
    for (int i = 0; i < 16; ++i) vin[j4 + i][d] = sf[i];
  }
  __syncthreads();

  // ---- phase 2: gt compute. thread: atom a = t&63, o-group oh = t>>6 (4 o's) ----
  int a = t & 63, oh = t >> 6;
  float acc[48];
#pragma unroll
  for (int i = 0; i < 48; ++i) acc[i] = 0.f;
  const float* Wb = filt + (size_t)(oq * 16 + oh * 4) * 792;  // wave-uniform base
#pragma unroll 1
  for (int dc = 0; dc < 4; ++dc) {
    float v[16];
#pragma unroll
    for (int i = 0; i < 16; ++i) v[i] = vin[a][dc * 16 + i];
#pragma unroll
    for (int o4 = 0; o4 < 4; ++o4) {
#pragma unroll
      for (int f = 0; f < 12; ++f) {
        const float* wp = Wb + o4 * 792 + f * 66 + dc * 16;  // uniform -> s_load
#pragma unroll
        for (int i = 0; i < 16; ++i) acc[o4 * 12 + f] += v[i] * wp[i];
      }
    }
  }
  // stage to sg[o_local][a*12+f]
#pragma unroll
  for (int o4 = 0; o4 < 4; ++o4) {
#pragma unroll
    for (int f = 0; f < 12; ++f) sg[oh * 4 + o4][a * 12 + f] = bf16_1(acc[o4 * 12 + f]);
  }
  __syncthreads();

  // ---- phase 3: 192 dense 128B segments -> gtt ----
  if (t < 192) {
    int ql = t >> 4, ol = t & 15;
    uint4* dst = (uint4*)(gtt + (size_t)(ks * 12 + ql) * 4096 + (oq * 16 + ol) * 64);
    const uint4* src = (const uint4*)(&sg[ol][ql * 64]);
#pragma unroll
    for (int i = 0; i < 8; ++i) dst[i] = src[i];
  }
}

// ---------------- k_big: split-K GEMM, 3-buffer counted-vmcnt pipeline (R3-measured) ----------------
__launch_bounds__(256, 2)
__global__ void k_big(const unsigned short* __restrict__ connt,
                      const unsigned short* __restrict__ gtt, float* __restrict__ part) {
  __shared__ __align__(16) unsigned short smem[36864];  // 3 x (16KB conn + 8KB gt) = 72 KB
  int t = threadIdx.x, lane = t & 63, w = t >> 6;
  int atile = blockIdx.x, ks = blockIdx.y;
  const unsigned short* ct = connt + (size_t)(atile * NSPLIT + ks) * (NKB * 8192);
  const unsigned short* gs = gtt + (size_t)ks * (NKB * 4096);

  int rl = lane >> 3, sl = lane & 7;
  int cs = sl ^ rl;

  int cSrc[4], gSrc[2], cDst[4], gDst[2];
#pragma unroll
  for (int j = 0; j < 4; ++j) {
    cSrc[j] = (w * 32 + j * 8 + rl) * 64 + cs * 8;
    cDst[j] = (w * 32 + j * 8) * 64;          // wave-uniform LDS base (glds appends lane*16B)
  }
#pragma unroll
  for (int j = 0; j < 2; ++j) {
    gSrc[j] = (w * 16 + j * 8 + rl) * 64 + cs * 8;
    gDst[j] = 8192 + (w * 16 + j * 8) * 64;
  }

  f32x16 acc0, acc1;
#pragma unroll
  for (int i = 0; i < 16; ++i) { acc0[i] = 0.f; acc1[i] = 0.f; }

  int oh = w >> 1, ah = w & 1;
  int orow = oh * 32 + (lane & 31);
  int arow = ah * 64 + (lane & 31);
  int sw = lane & 7;
  int khalf = lane >> 5;

  // prologue: prefetch tiles 0,1 (12 vm-ops/wave outstanding)
#pragma unroll
  for (int p = 0; p < 2; ++p) {
    unsigned short* base = smem + p * 12288;
#pragma unroll
    for (int j = 0; j < 4; ++j) GLOAD16(base + cDst[j], ct + p * 8192 + cSrc[j]);
#pragma unroll
    for (int j = 0; j < 2; ++j) GLOAD16(base + gDst[j], gs + p * 4096 + gSrc[j]);
  }

#pragma unroll
  for (int kb = 0; kb < NKB; ++kb) {
    // outstanding here: tiles kb (6) + kb+1 (6). vmcnt(6) => tile kb landed.
    if (kb < NKB - 1) VMWAIT(6);
    else VMWAIT(0);
    __builtin_amdgcn_s_barrier();          // collective visibility of tile kb
    asm volatile("" ::: "memory");         // keep LDS reads below the barrier
    if (kb + 2 < NKB) {                    // issue tile kb+2 into buf (kb-1)%3 (reads done)
      unsigned short* base = smem + ((kb + 2) % 3) * 12288;
#pragma unroll
      for (int j = 0; j < 4; ++j) GLOAD16(base + cDst[j], ct + (kb + 2) * 8192 + cSrc[j]);
#pragma unroll
      for (int j = 0; j < 2; ++j) GLOAD16(base + gDst[j], gs + (kb + 2) * 4096 + gSrc[j]);
    }
    const unsigned short* cb = smem + (kb % 3) * 12288;
    const unsigned short* gb = cb + 8192;
#pragma unroll
    for (int kk = 0; kk < 4; ++kk) {
      int c = kk * 2 + khalf;
      int coff = ((c ^ sw) << 3);
      short8 af = *(const short8*)(gb + orow * 64 + coff);
      short8 b0 = *(const short8*)(cb + arow * 64 + coff);
      short8 b1 = *(const short8*)(cb + (arow + 32) * 64 + coff);
      acc0 = __builtin_amdgcn_mfma_f32_32x32x16_bf16(af, b0, acc0, 0, 0, 0);
      acc1 = __builtin_amdgcn_mfma_f32_32x32x16_bf16(af, b1, acc1, 0, 0, 0);
    }
  }

  float* pp = part + (size_t)ks * (64 * 2048);
  int a0 = atile * 128 + ah * 64 + (lane & 31);
  int ob = oh * 32 + 4 * khalf;
#pragma unroll
  for (int rg = 0; rg < 16; ++rg) {
    int o = ob + (rg & 3) + 8 * (rg >> 2);
    pp[o * 2048 + a0] = acc0[rg];
    pp[o * 2048 + a0 + 32] = acc1[rg];
  }
}

// ---------------- k_red: final epilogue (R5-validated body) ----------------
// 512 blocks; thread quarter q sums splits [q*8,q*8+8); quarters combined in LDS.
__global__ void k_red(const float* __restrict__ part, const float* __restrict__ bt,
                      const float* __restrict__ xt, float* __restrict__ curt,
                      float* __restrict__ outp, int residual, int final_layer) {
  __shared__ __align__(16) float4 rbuf[192];
  int t = threadIdx.x, bid = blockIdx.x;
  int i4 = bid * 64 + (t & 63);             // float4 index, 0..32767; layout [o][m]
  int quar = t >> 6;
  int sbase = quar * 8;
  float4 s = {0.f, 0.f, 0.f, 0.f};
#pragma unroll
  for (int k = 0; k < 8; ++k) {
    float4 p = ((const float4*)part)[(size_t)(sbase + k) * 32768 + i4];
    s.x += p.x; s.y += p.y; s.z += p.z; s.w += p.w;
  }
  if (quar) rbuf[(quar - 1) * 64 + (t & 63)] = s;
  __syncthreads();
  if (!quar) {                              // t in [0,64)
    float4 a = rbuf[t], b2 = rbuf[64 + t], c2 = rbuf[128 + t];
    float4 b = ((const float4*)bt)[i4];
    s.x += a.x + b2.x + c2.x + b.x;
    s.y += a.y + b2.y + c2.y + b.y;
    s.z += a.z + b2.z + c2.z + b.z;
    s.w += a.w + b2.w + c2.w + b.w;
    if (residual) {
      float4 rr = ((const float4*)xt)[i4];
      s.x += rr.x; s.y += rr.y; s.z += rr.z; s.w += rr.w;
    }
    s.x = fmaxf(s.x, 0.f); s.y = fmaxf(s.y, 0.f);
    s.z = fmaxf(s.z, 0.f); s.w = fmaxf(s.w, 0.f);
    ((float4*)curt)[i4] = s;
    if (final_layer) {
      int idx = i4 * 4;
      int o = idx >> 11, m = idx & 2047;
      outp[(m + 0) * 64 + o] = s.x;
      outp[(m + 1) * 64 + o] = s.y;
      outp[(m + 2) * 64 + o] = s.z;
      outp[(m + 3) * 64 + o] = s.w;
    }
  }
}

extern "C" void kernel_launch(void* const* d_in, const int* in_sizes, int n_in,
                              void* d_out, int out_size, void* d_ws, size_t ws_size,
                              hipStream_t stream) {
  const float* x    = (const float*)d_in[0];  // (2048, 64)
  const float* conn = (const float*)d_in[1];  // (2048, 2048, 12)
  const float* bond = (const float*)d_in[2];  // (2048, 12, 2)
  const float* f0   = (const float*)d_in[3];  // (64, 12, 66)
  const float* f1   = (const float*)d_in[4];
  float* out = (float*)d_out;                 // (2048, 64)

  char* ws = (char*)d_ws;
  float* xt   = (float*)(ws + 0);              // 64x2048 fp32            512 KB
  float* curt = (float*)(ws + 524288);         // 64x2048 fp32            512 KB
  float* bt0  = (float*)(ws + 1048576);        // 64x2048 fp32            512 KB
  float* bt1  = (float*)(ws + 1572864);        // 64x2048 fp32            512 KB
  unsigned short* gtt = (unsigned short*)(ws + 2097152);     // tiled gt    3 MB
  float* part = (float*)(ws + 5242880);        // 32 x 64x2048 fp32       16 MB
  unsigned short* connt = (unsigned short*)(ws + 33554432);  // tiled conn  96 MB

  k_pre<<<6688, 256, 0, stream>>>(x, xt, bond, f0, f1, bt0, bt1, conn, connt);

  // L0: vin = x
  k_rg<<<dim3(4, NSPLIT), 256, 0, stream>>>(part, xt, bt0, f0, gtt, 0, 0);
  k_big<<<dim3(16, NSPLIT), 256, 0, stream>>>(connt, gtt, part);
  // L1: vin = relu(cc0 + bt0)
  k_rg<<<dim3(4, NSPLIT), 256, 0, stream>>>(part, xt, bt0, f0, gtt, 1, 0);
  k_big<<<dim3(16, NSPLIT), 256, 0, stream>>>(connt, gtt, part);
  // L2: vin = relu(cc1 + bt0 + x)
  k_rg<<<dim3(4, NSPLIT), 256, 0, stream>>>(part, xt, bt0, f1, gtt, 1, 1);
  k_big<<<dim3(16, NSPLIT), 256, 0, stream>>>(connt, gtt, part);
  // L3: vin = relu(cc2 + bt1)
  k_rg<<<dim3(4, NSPLIT), 256, 0, stream>>>(part, xt, bt1, f1, gtt, 1, 0);
  k_big<<<dim3(16, NSPLIT), 256, 0, stream>>>(connt, gtt, part);
  // final: out = relu(cc3 + bt1 + x), with [a][o] permute
  k_red<<<512, 256, 0, stream>>>(part, bt1, xt, curt, out, 1, 1);
}

// Round 7
// 450.269 us; speedup vs baseline: 2.6415x; 1.2186x over previous
//
#include <hip/hip_runtime.h>

// ChemResBlock: A=2048 atoms, D=64 depth, F=12 taps.
// out[a,o] = sum_{n,f} conn[a][n*12+f] * Gt[o][n*12+f] + bterm[a,o]
// R13: model reconciled: ~234us of dur_us is harness ws re-poison (2x117us
// fills of the 768MB workspace) -- untouchable. Our work ~220us in the R1
// structure. R6's k_rg fusion REVERTED (128-block latency-bound, +90us).
// This round: R4-validated k_g/k_red restored; merged k_pre kept; k_big
// redesigned for occupancy: 64-row a-tiles, 48KB LDS (3 buffers x 16KB),
// 3 blocks/CU (was 2), grid (32,32), vmcnt(4) steady pipeline.
// k_big mapping is a mechanical halving of the R3-measured 128-row kernel.

#define A_N 2048
#define D_N 64
#define F_N 12
#define K_TOTAL (A_N * F_N)        // 24576
#define NSPLIT 32
#define KSEG (K_TOTAL / NSPLIT)    // 768
#define BK 64
#define NKB (KSEG / BK)            // 12

typedef short short8 __attribute__((ext_vector_type(8)));
typedef float f32x16 __attribute__((ext_vector_type(16)));

#define GLOAD16(ldsp, gp)                                                        \
  __builtin_amdgcn_global_load_lds(                                              \
      (const __attribute__((address_space(1))) void*)(gp),                       \
      (__attribute__((address_space(3))) void*)(ldsp), 16, 0, 0)

#define VMWAIT(n) asm volatile("s_waitcnt vmcnt(" #n ")" ::: "memory")

// pack two floats to bf16 pair with round-to-nearest-even
__device__ __forceinline__ unsigned pk_bf16(float a, float b) {
  unsigned ua = __float_as_uint(a);
  unsigned ub = __float_as_uint(b);
  ua += 0x7fffu + ((ua >> 16) & 1u);
  ub += 0x7fffu + ((ub >> 16) & 1u);
  return (ua >> 16) | (ub & 0xffff0000u);
}

__device__ __forceinline__ unsigned short bf16_1(float v) {
  unsigned u = __float_as_uint(v);
  u += 0x7fffu + ((u >> 16) & 1u);
  return (unsigned short)(u >> 16);
}

// ---------------- k_pre: x transpose + bterm + conn->bf16 tiled convert ----------------
// blocks 0..31: xt transpose; 32..543: bterm; 544..6687: cvt (6144 tiles).
__global__ void k_pre(const float* __restrict__ x, float* __restrict__ xt,
                      const float* __restrict__ bond, const float* __restrict__ f0,
                      const float* __restrict__ f1, float* __restrict__ bt0,
                      float* __restrict__ bt1, const float* __restrict__ conn,
                      unsigned short* __restrict__ connt) {
  int t = threadIdx.x, b = blockIdx.x;
  if (b < 32) {
    __shared__ float ld[64][65];
    int m0 = b * 64;
    int r = t >> 2, cq = (t & 3) * 16;
    const float4* src = (const float4*)(x + (size_t)(m0 + r) * 64 + cq);
#pragma unroll
    for (int i = 0; i < 4; ++i) {
      float4 v = src[i];
      ld[r][cq + i * 4 + 0] = v.x;
      ld[r][cq + i * 4 + 1] = v.y;
      ld[r][cq + i * 4 + 2] = v.z;
      ld[r][cq + i * 4 + 3] = v.w;
    }
    __syncthreads();
    int c = t >> 2, ml0 = (t & 3) * 16;
    float4* dst = (float4*)(xt + (size_t)c * 2048 + m0 + ml0);
#pragma unroll
    for (int i = 0; i < 4; ++i) {
      float4 v;
      v.x = ld[ml0 + i * 4 + 0][c];
      v.y = ld[ml0 + i * 4 + 1][c];
      v.z = ld[ml0 + i * 4 + 2][c];
      v.w = ld[ml0 + i * 4 + 3][c];
      dst[i] = v;
    }
  } else if (b < 544) {
    int b2 = b - 32;                   // 0..511
    int a = (b2 & 31) * 64 + (t & 63);
    int o = (b2 >> 5) * 4 + (t >> 6);
    float s0 = 0.f, s1 = 0.f;
#pragma unroll
    for (int f = 0; f < F_N; ++f) {
#pragma unroll
      for (int j = 0; j < 2; ++j) {
        float bv = bond[a * 24 + f * 2 + j];
        s0 += bv * f0[o * 792 + f * 66 + 64 + j];
        s1 += bv * f1[o * 792 + f * 66 + 64 + j];
      }
    }
    bt0[o * 2048 + a] = s0;
    bt1[o * 2048 + a] = s1;
  } else {
    int i = b - 544;                   // 0..6143: tile (atile, ks, kb)
    int atile = i / 384;
    int r2 = i % 384;
    int ks = r2 / 12, kb = r2 % 12;
    const float* src = conn + (size_t)(atile * 128) * K_TOTAL + ks * KSEG + kb * 64;
    unsigned short* dst = connt + (size_t)((atile * NSPLIT + ks) * NKB + kb) * 8192;
    int r0 = t >> 3, c0 = (t & 7) * 8;
#pragma unroll
    for (int q = 0; q < 4; ++q) {
      int row = r0 + q * 32;
      const float4* s4 = (const float4*)(src + (size_t)row * K_TOTAL + c0);
      float4 a = s4[0], bb = s4[1];
      uint4 p;
      p.x = pk_bf16(a.x, a.y);
      p.y = pk_bf16(a.z, a.w);
      p.z = pk_bf16(bb.x, bb.y);
      p.w = pk_bf16(bb.z, bb.w);
      *(uint4*)(dst + row * 64 + c0) = p;
    }
  }
}

// ---------------- k_g: Gt -> tiled gtt[q][o][c], q = k>>6 (R4-validated) ----------------
__global__ void k_g(const float* __restrict__ vt, const float* __restrict__ filt,
                    unsigned short* __restrict__ gtt) {
  __shared__ __align__(16) float WT[64][12];        // 3 KB
  __shared__ __align__(16) unsigned short sg[6144]; // 12 KB staged output tile
  int o = blockIdx.y, bx = blockIdx.x;
  int t = threadIdx.x;
  for (int i = t; i < 768; i += 256) {
    int d = i / 12, f = i % 12;
    WT[d][f] = filt[o * 792 + f * 66 + d];
  }
  __syncthreads();
  int n0 = bx * 512 + t;                       // second atom at n0+256
  float acc0[12], acc1[12];
#pragma unroll
  for (int f = 0; f < 12; ++f) { acc0[f] = 0.f; acc1[f] = 0.f; }
#pragma unroll 4
  for (int d = 0; d < 64; ++d) {
    float v0 = vt[d * 2048 + n0];
    float v1 = vt[d * 2048 + n0 + 256];
    const float4* wp = (const float4*)WT[d];
    float4 w0 = wp[0], w1 = wp[1], w2 = wp[2];
    acc0[0] += v0 * w0.x;  acc0[1] += v0 * w0.y;  acc0[2]  += v0 * w0.z;  acc0[3]  += v0 * w0.w;
    acc0[4] += v0 * w1.x;  acc0[5] += v0 * w1.y;  acc0[6]  += v0 * w1.z;  acc0[7]  += v0 * w1.w;
    acc0[8] += v0 * w2.x;  acc0[9] += v0 * w2.y;  acc0[10] += v0 * w2.z;  acc0[11] += v0 * w2.w;
    acc1[0] += v1 * w0.x;  acc1[1] += v1 * w0.y;  acc1[2]  += v1 * w0.z;  acc1[3]  += v1 * w0.w;
    acc1[4] += v1 * w1.x;  acc1[5] += v1 * w1.y;  acc1[6]  += v1 * w1.z;  acc1[7]  += v1 * w1.w;
    acc1[8] += v1 * w2.x;  acc1[9] += v1 * w2.y;  acc1[10] += v1 * w2.z;  acc1[11] += v1 * w2.w;
  }
#pragma unroll
  for (int f = 0; f < F_N; ++f) {
    sg[t * 12 + f] = bf16_1(acc0[f]);
    sg[t * 12 + 3072 + f] = bf16_1(acc1[f]);
  }
  __syncthreads();
  // 768 chunks of 16B; chunk m covers local k [m*8, m*8+8)
  unsigned short* gbase = gtt + (size_t)(bx * 96) * 4096 + o * 64;
#pragma unroll
  for (int j = 0; j < 3; ++j) {
    int m = t + j * 256;
    *(uint4*)(gbase + (size_t)(m >> 3) * 4096 + (m & 7) * 8) = *(const uint4*)(sg + m * 8);
  }
}

// ---------------- k_big: split-K GEMM, 64-row a-tiles, 3 blocks/CU ----------------
// grid (32, NSPLIT). Mechanical halving of the R3-measured 128-row kernel:
// acc1/b1 deleted, arow = ah*32+lane31, connt base += (atile&1)*4096.
__launch_bounds__(256, 3)
__global__ void k_big(const unsigned short* __restrict__ connt,
                      const unsigned short* __restrict__ gtt, float* __restrict__ part) {
  __shared__ __align__(16) unsigned short smem[24576];  // 3 x (8KB conn + 8KB gt) = 48 KB
  int t = threadIdx.x, lane = t & 63, w = t >> 6;
  int atile = blockIdx.x, ks = blockIdx.y;      // atile: 64-row tile, 0..31
  int a128 = atile >> 1, half = atile & 1;
  const unsigned short* ct =
      connt + (size_t)(a128 * NSPLIT + ks) * (NKB * 8192) + half * 4096;
  const unsigned short* gs = gtt + (size_t)ks * (NKB * 4096);

  int rl = lane >> 3, sl = lane & 7;
  int cs = sl ^ rl;

  int cSrc[2], gSrc[2], cDst[2], gDst[2];
#pragma unroll
  for (int j = 0; j < 2; ++j) {
    int row = w * 16 + j * 8 + rl;              // 4 waves x 16 rows = 64
    cSrc[j] = row * 64 + cs * 8;
    cDst[j] = (w * 16 + j * 8) * 64;            // wave-uniform LDS base
    gSrc[j] = row * 64 + cs * 8;
    gDst[j] = 4096 + (w * 16 + j * 8) * 64;
  }

  f32x16 acc0;
#pragma unroll
  for (int i = 0; i < 16; ++i) acc0[i] = 0.f;

  int oh = w >> 1, ah = w & 1;
  int orow = oh * 32 + (lane & 31);
  int arow = ah * 32 + (lane & 31);
  int sw = lane & 7;
  int khalf = lane >> 5;

  // prologue: prefetch tiles 0,1 (8 vm-ops/wave outstanding)
#pragma unroll
  for (int p = 0; p < 2; ++p) {
    unsigned short* base = smem + p * 8192;
#pragma unroll
    for (int j = 0; j < 2; ++j) GLOAD16(base + cDst[j], ct + p * 8192 + cSrc[j]);
#pragma unroll
    for (int j = 0; j < 2; ++j) GLOAD16(base + gDst[j], gs + p * 4096 + gSrc[j]);
  }

#pragma unroll
  for (int kb = 0; kb < NKB; ++kb) {
    // outstanding here: tiles kb (4) + kb+1 (4). vmcnt(4) => tile kb landed.
    if (kb < NKB - 1) VMWAIT(4);
    else VMWAIT(0);
    __builtin_amdgcn_s_barrier();          // collective visibility of tile kb
    asm volatile("" ::: "memory");         // keep LDS reads below the barrier
    if (kb + 2 < NKB) {                    // issue tile kb+2 into buf (kb-1)%3 (reads done)
      unsigned short* base = smem + ((kb + 2) % 3) * 8192;
#pragma unroll
      for (int j = 0; j < 2; ++j) GLOAD16(base + cDst[j], ct + (kb + 2) * 8192 + cSrc[j]);
#pragma unroll
      for (int j = 0; j < 2; ++j) GLOAD16(base + gDst[j], gs + (kb + 2) * 4096 + gSrc[j]);
    }
    const unsigned short* cb = smem + (kb % 3) * 8192;
    const unsigned short* gb = cb + 4096;
#pragma unroll
    for (int kk = 0; kk < 4; ++kk) {
      int c = kk * 2 + khalf;
      int coff = ((c ^ sw) << 3);
      short8 af = *(const short8*)(gb + orow * 64 + coff);
      short8 b0 = *(const short8*)(cb + arow * 64 + coff);
      acc0 = __builtin_amdgcn_mfma_f32_32x32x16_bf16(af, b0, acc0, 0, 0, 0);
    }
  }

  float* pp = part + (size_t)ks * (64 * 2048);
  int a0 = atile * 64 + ah * 32 + (lane & 31);
  int ob = oh * 32 + 4 * khalf;
#pragma unroll
  for (int rg = 0; rg < 16; ++rg) {
    int o = ob + (rg & 3) + 8 * (rg >> 2);
    pp[o * 2048 + a0] = acc0[rg];
  }
}

// ---------------- k_red: sum partials + bterm (+x) + relu (R4-validated) ----------------
// 256 blocks x 256 threads; thread sums 16 of 32 splits, halves combined in LDS.
__global__ void k_red(const float* __restrict__ part, const float* __restrict__ bt,
                      const float* __restrict__ xt, float* __restrict__ curt,
                      float* __restrict__ outp, int residual, int final_layer) {
  __shared__ float4 buf[128];
  int t = threadIdx.x;
  int i4 = blockIdx.x * 128 + (t & 127);    // float4 index, 0..32767; layout [o][m]
  int half = t >> 7;
  int sbase = half * 16;
  float4 s = {0.f, 0.f, 0.f, 0.f};
#pragma unroll
  for (int k = 0; k < 16; ++k) {
    float4 p = ((const float4*)part)[(size_t)(sbase + k) * 32768 + i4];
    s.x += p.x; s.y += p.y; s.z += p.z; s.w += p.w;
  }
  if (half) buf[t & 127] = s;
  __syncthreads();
  if (!half) {
    float4 q = buf[t];
    float4 b = ((const float4*)bt)[i4];
    s.x += q.x + b.x; s.y += q.y + b.y; s.z += q.z + b.z; s.w += q.w + b.w;
    if (residual) {
      float4 rr = ((const float4*)xt)[i4];
      s.x += rr.x; s.y += rr.y; s.z += rr.z; s.w += rr.w;
    }
    s.x = fmaxf(s.x, 0.f); s.y = fmaxf(s.y, 0.f);
    s.z = fmaxf(s.z, 0.f); s.w = fmaxf(s.w, 0.f);
    ((float4*)curt)[i4] = s;
    if (final_layer) {
      int idx = i4 * 4;
      int o = idx >> 11, m = idx & 2047;
      outp[(m + 0) * 64 + o] = s.x;
      outp[(m + 1) * 64 + o] = s.y;
      outp[(m + 2) * 64 + o] = s.z;
      outp[(m + 3) * 64 + o] = s.w;
    }
  }
}

extern "C" void kernel_launch(void* const* d_in, const int* in_sizes, int n_in,
                              void* d_out, int out_size, void* d_ws, size_t ws_size,
                              hipStream_t stream) {
  const float* x    = (const float*)d_in[0];  // (2048, 64)
  const float* conn = (const float*)d_in[1];  // (2048, 2048, 12)
  const float* bond = (const float*)d_in[2];  // (2048, 12, 2)
  const float* f0   = (const float*)d_in[3];  // (64, 12, 66)
  const float* f1   = (const float*)d_in[4];
  float* out = (float*)d_out;                 // (2048, 64)

  char* ws = (char*)d_ws;
  float* xt   = (float*)(ws + 0);              // 64x2048 fp32            512 KB
  float* curt = (float*)(ws + 524288);         // 64x2048 fp32            512 KB
  float* bt0  = (float*)(ws + 1048576);        // 64x2048 fp32            512 KB
  float* bt1  = (float*)(ws + 1572864);        // 64x2048 fp32            512 KB
  unsigned short* gtt = (unsigned short*)(ws + 2097152);     // tiled gt    3 MB
  float* part = (float*)(ws + 5242880);        // 32 x 64x2048 fp32       16 MB
  unsigned short* connt = (unsigned short*)(ws + 33554432);  // tiled conn  96 MB

  k_pre<<<6688, 256, 0, stream>>>(x, xt, bond, f0, f1, bt0, bt1, conn, connt);

  for (int layer = 0; layer < 4; ++layer) {
    const float* filt = (layer < 2) ? f0 : f1;
    const float* bt   = (layer < 2) ? bt0 : bt1;
    const float* vin  = (layer == 0) ? xt : curt;
    k_g<<<dim3(4, 64), 256, 0, stream>>>(vin, filt, gtt);
    k_big<<<dim3(32, NSPLIT), 256, 0, stream>>>(connt, gtt, part);
    k_red<<<256, 256, 0, stream>>>(part, bt, xt, curt, out, layer & 1, layer == 3);
  }
}

// Round 8
// 442.810 us; speedup vs baseline: 2.6860x; 1.0168x over previous
//
#include <hip/hip_runtime.h>

// ChemResBlock: A=2048 atoms, D=64 depth, F=12 taps.
// out[a,o] = sum_{n,f} conn[a][n*12+f] * Gt[o][n*12+f] + bterm[a,o]
// R14: NSPLIT 32->16. R7 analysis: k_big is fabric-BW-bound (~6.8 TB/s
// aggregate delivery ceiling, R3-measured) AND had a 1.33-wave block
// scheduling tail (1024 blocks vs 768 resident slots). At NSPLIT=16:
// grid (32,16)=512 blocks -> all co-resident (no tail), NKB=24 amortizes
// prologue/epilogue 2x, part round-trip halves (32->16 MB/layer).
// connt tiled layout is IDENTICAL under (16,24) -- (ks,kb) lex order covers
// q=k>>6 in the same sequence -- so k_pre/k_g are byte-unchanged.
// k_big body is the R7-validated 64-row kernel; only grid/loop constants.

#define A_N 2048
#define D_N 64
#define F_N 12
#define K_TOTAL (A_N * F_N)        // 24576
#define NSPLIT 16
#define KSEG (K_TOTAL / NSPLIT)    // 1536
#define BK 64
#define NKB (KSEG / BK)            // 24

typedef short short8 __attribute__((ext_vector_type(8)));
typedef float f32x16 __attribute__((ext_vector_type(16)));

#define GLOAD16(ldsp, gp)                                                        \
  __builtin_amdgcn_global_load_lds(                                              \
      (const __attribute__((address_space(1))) void*)(gp),                       \
      (__attribute__((address_space(3))) void*)(ldsp), 16, 0, 0)

#define VMWAIT(n) asm volatile("s_waitcnt vmcnt(" #n ")" ::: "memory")

// pack two floats to bf16 pair with round-to-nearest-even
__device__ __forceinline__ unsigned pk_bf16(float a, float b) {
  unsigned ua = __float_as_uint(a);
  unsigned ub = __float_as_uint(b);
  ua += 0x7fffu + ((ua >> 16) & 1u);
  ub += 0x7fffu + ((ub >> 16) & 1u);
  return (ua >> 16) | (ub & 0xffff0000u);
}

__device__ __forceinline__ unsigned short bf16_1(float v) {
  unsigned u = __float_as_uint(v);
  u += 0x7fffu + ((u >> 16) & 1u);
  return (unsigned short)(u >> 16);
}

// ---------------- k_pre: x transpose + bterm + conn->bf16 tiled convert ----------------
// blocks 0..31: xt transpose; 32..543: bterm; 544..6687: cvt (6144 tiles).
__global__ void k_pre(const float* __restrict__ x, float* __restrict__ xt,
                      const float* __restrict__ bond, const float* __restrict__ f0,
                      const float* __restrict__ f1, float* __restrict__ bt0,
                      float* __restrict__ bt1, const float* __restrict__ conn,
                      unsigned short* __restrict__ connt) {
  int t = threadIdx.x, b = blockIdx.x;
  if (b < 32) {
    __shared__ float ld[64][65];
    int m0 = b * 64;
    int r = t >> 2, cq = (t & 3) * 16;
    const float4* src = (const float4*)(x + (size_t)(m0 + r) * 64 + cq);
#pragma unroll
    for (int i = 0; i < 4; ++i) {
      float4 v = src[i];
      ld[r][cq + i * 4 + 0] = v.x;
      ld[r][cq + i * 4 + 1] = v.y;
      ld[r][cq + i * 4 + 2] = v.z;
      ld[r][cq + i * 4 + 3] = v.w;
    }
    __syncthreads();
    int c = t >> 2, ml0 = (t & 3) * 16;
    float4* dst = (float4*)(xt + (size_t)c * 2048 + m0 + ml0);
#pragma unroll
    for (int i = 0; i < 4; ++i) {
      float4 v;
      v.x = ld[ml0 + i * 4 + 0][c];
      v.y = ld[ml0 + i * 4 + 1][c];
      v.z = ld[ml0 + i * 4 + 2][c];
      v.w = ld[ml0 + i * 4 + 3][c];
      dst[i] = v;
    }
  } else if (b < 544) {
    int b2 = b - 32;                   // 0..511
    int a = (b2 & 31) * 64 + (t & 63);
    int o = (b2 >> 5) * 4 + (t >> 6);
    float s0 = 0.f, s1 = 0.f;
#pragma unroll
    for (int f = 0; f < F_N; ++f) {
#pragma unroll
      for (int j = 0; j < 2; ++j) {
        float bv = bond[a * 24 + f * 2 + j];
        s0 += bv * f0[o * 792 + f * 66 + 64 + j];
        s1 += bv * f1[o * 792 + f * 66 + 64 + j];
      }
    }
    bt0[o * 2048 + a] = s0;
    bt1[o * 2048 + a] = s1;
  } else {
    int i = b - 544;                   // 0..6143: tile (atile, ks, kb)
    int atile = i / 384;               // 384 = NSPLIT*NKB (layout-invariant)
    int r2 = i % 384;
    int ks = r2 / NKB, kb = r2 % NKB;
    const float* src = conn + (size_t)(atile * 128) * K_TOTAL + ks * KSEG + kb * 64;
    unsigned short* dst = connt + (size_t)((atile * NSPLIT + ks) * NKB + kb) * 8192;
    int r0 = t >> 3, c0 = (t & 7) * 8;
#pragma unroll
    for (int q = 0; q < 4; ++q) {
      int row = r0 + q * 32;
      const float4* s4 = (const float4*)(src + (size_t)row * K_TOTAL + c0);
      float4 a = s4[0], bb = s4[1];
      uint4 p;
      p.x = pk_bf16(a.x, a.y);
      p.y = pk_bf16(a.z, a.w);
      p.z = pk_bf16(bb.x, bb.y);
      p.w = pk_bf16(bb.z, bb.w);
      *(uint4*)(dst + row * 64 + c0) = p;
    }
  }
}

// ---------------- k_g: Gt -> tiled gtt[q][o][c], q = k>>6 (R4-validated) ----------------
__global__ void k_g(const float* __restrict__ vt, const float* __restrict__ filt,
                    unsigned short* __restrict__ gtt) {
  __shared__ __align__(16) float WT[64][12];        // 3 KB
  __shared__ __align__(16) unsigned short sg[6144]; // 12 KB staged output tile
  int o = blockIdx.y, bx = blockIdx.x;
  int t = threadIdx.x;
  for (int i = t; i < 768; i += 256) {
    int d = i / 12, f = i % 12;
    WT[d][f] = filt[o * 792 + f * 66 + d];
  }
  __syncthreads();
  int n0 = bx * 512 + t;                       // second atom at n0+256
  float acc0[12], acc1[12];
#pragma unroll
  for (int f = 0; f < 12; ++f) { acc0[f] = 0.f; acc1[f] = 0.f; }
#pragma unroll 4
  for (int d = 0; d < 64; ++d) {
    float v0 = vt[d * 2048 + n0];
    float v1 = vt[d * 2048 + n0 + 256];
    const float4* wp = (const float4*)WT[d];
    float4 w0 = wp[0], w1 = wp[1], w2 = wp[2];
    acc0[0] += v0 * w0.x;  acc0[1] += v0 * w0.y;  acc0[2]  += v0 * w0.z;  acc0[3]  += v0 * w0.w;
    acc0[4] += v0 * w1.x;  acc0[5] += v0 * w1.y;  acc0[6]  += v0 * w1.z;  acc0[7]  += v0 * w1.w;
    acc0[8] += v0 * w2.x;  acc0[9] += v0 * w2.y;  acc0[10] += v0 * w2.z;  acc0[11] += v0 * w2.w;
    acc1[0] += v1 * w0.x;  acc1[1] += v1 * w0.y;  acc1[2]  += v1 * w0.z;  acc1[3]  += v1 * w0.w;
    acc1[4] += v1 * w1.x;  acc1[5] += v1 * w1.y;  acc1[6]  += v1 * w1.z;  acc1[7]  += v1 * w1.w;
    acc1[8] += v1 * w2.x;  acc1[9] += v1 * w2.y;  acc1[10] += v1 * w2.z;  acc1[11] += v1 * w2.w;
  }
#pragma unroll
  for (int f = 0; f < F_N; ++f) {
    sg[t * 12 + f] = bf16_1(acc0[f]);
    sg[t * 12 + 3072 + f] = bf16_1(acc1[f]);
  }
  __syncthreads();
  // 768 chunks of 16B; chunk m covers local k [m*8, m*8+8)
  unsigned short* gbase = gtt + (size_t)(bx * 96) * 4096 + o * 64;
#pragma unroll
  for (int j = 0; j < 3; ++j) {
    int m = t + j * 256;
    *(uint4*)(gbase + (size_t)(m >> 3) * 4096 + (m & 7) * 8) = *(const uint4*)(sg + m * 8);
  }
}

// ---------------- k_big: split-K GEMM, 64-row a-tiles, 3 blocks/CU ----------------
// grid (32, NSPLIT=16) = 512 blocks -> fully co-resident, no scheduling tail.
__launch_bounds__(256, 3)
__global__ void k_big(const unsigned short* __restrict__ connt,
                      const unsigned short* __restrict__ gtt, float* __restrict__ part) {
  __shared__ __align__(16) unsigned short smem[24576];  // 3 x (8KB conn + 8KB gt) = 48 KB
  int t = threadIdx.x, lane = t & 63, w = t >> 6;
  int atile = blockIdx.x, ks = blockIdx.y;      // atile: 64-row tile, 0..31
  int a128 = atile >> 1, half = atile & 1;
  const unsigned short* ct =
      connt + (size_t)(a128 * NSPLIT + ks) * (NKB * 8192) + half * 4096;
  const unsigned short* gs = gtt + (size_t)ks * (NKB * 4096);

  int rl = lane >> 3, sl = lane & 7;
  int cs = sl ^ rl;

  int cSrc[2], gSrc[2], cDst[2], gDst[2];
#pragma unroll
  for (int j = 0; j < 2; ++j) {
    int row = w * 16 + j * 8 + rl;              // 4 waves x 16 rows = 64
    cSrc[j] = row * 64 + cs * 8;
    cDst[j] = (w * 16 + j * 8) * 64;            // wave-uniform LDS base
    gSrc[j] = row * 64 + cs * 8;
    gDst[j] = 4096 + (w * 16 + j * 8) * 64;
  }

  f32x16 acc0;
#pragma unroll
  for (int i = 0; i < 16; ++i) acc0[i] = 0.f;

  int oh = w >> 1, ah = w & 1;
  int orow = oh * 32 + (lane & 31);
  int arow = ah * 32 + (lane & 31);
  int sw = lane & 7;
  int khalf = lane >> 5;

  // prologue: prefetch tiles 0,1 (8 vm-ops/wave outstanding)
#pragma unroll
  for (int p = 0; p < 2; ++p) {
    unsigned short* base = smem + p * 8192;
#pragma unroll
    for (int j = 0; j < 2; ++j) GLOAD16(base + cDst[j], ct + p * 8192 + cSrc[j]);
#pragma unroll
    for (int j = 0; j < 2; ++j) GLOAD16(base + gDst[j], gs + p * 4096 + gSrc[j]);
  }

#pragma unroll
  for (int kb = 0; kb < NKB; ++kb) {
    // outstanding here: tiles kb (4) + kb+1 (4). vmcnt(4) => tile kb landed.
    if (kb < NKB - 1) VMWAIT(4);
    else VMWAIT(0);
    __builtin_amdgcn_s_barrier();          // collective visibility of tile kb
    asm volatile("" ::: "memory");         // keep LDS reads below the barrier
    if (kb + 2 < NKB) {                    // issue tile kb+2 into buf (kb-1)%3 (reads done)
      unsigned short* base = smem + ((kb + 2) % 3) * 8192;
#pragma unroll
      for (int j = 0; j < 2; ++j) GLOAD16(base + cDst[j], ct + (kb + 2) * 8192 + cSrc[j]);
#pragma unroll
      for (int j = 0; j < 2; ++j) GLOAD16(base + gDst[j], gs + (kb + 2) * 4096 + gSrc[j]);
    }
    const unsigned short* cb = smem + (kb % 3) * 8192;
    const unsigned short* gb = cb + 4096;
#pragma unroll
    for (int kk = 0; kk < 4; ++kk) {
      int c = kk * 2 + khalf;
      int coff = ((c ^ sw) << 3);
      short8 af = *(const short8*)(gb + orow * 64 + coff);
      short8 b0 = *(const short8*)(cb + arow * 64 + coff);
      acc0 = __builtin_amdgcn_mfma_f32_32x32x16_bf16(af, b0, acc0, 0, 0, 0);
    }
  }

  float* pp = part + (size_t)ks * (64 * 2048);
  int a0 = atile * 64 + ah * 32 + (lane & 31);
  int ob = oh * 32 + 4 * khalf;
#pragma unroll
  for (int rg = 0; rg < 16; ++rg) {
    int o = ob + (rg & 3) + 8 * (rg >> 2);
    pp[o * 2048 + a0] = acc0[rg];
  }
}

// ---------------- k_red: sum partials + bterm (+x) + relu ----------------
// 256 blocks x 256 threads; thread sums 8 of 16 splits, halves combined in LDS.
__global__ void k_red(const float* __restrict__ part, const float* __restrict__ bt,
                      const float* __restrict__ xt, float* __restrict__ curt,
                      float* __restrict__ outp, int residual, int final_layer) {
  __shared__ float4 buf[128];
  int t = threadIdx.x;
  int i4 = blockIdx.x * 128 + (t & 127);    // float4 index, 0..32767; layout [o][m]
  int half = t >> 7;
  int sbase = half * 8;
  float4 s = {0.f, 0.f, 0.f, 0.f};
#pragma unroll
  for (int k = 0; k < 8; ++k) {
    float4 p = ((const float4*)part)[(size_t)(sbase + k) * 32768 + i4];
    s.x += p.x; s.y += p.y; s.z += p.z; s.w += p.w;
  }
  if (half) buf[t & 127] = s;
  __syncthreads();
  if (!half) {
    float4 q = buf[t];
    float4 b = ((const float4*)bt)[i4];
    s.x += q.x + b.x; s.y += q.y + b.y; s.z += q.z + b.z; s.w += q.w + b.w;
    if (residual) {
      float4 rr = ((const float4*)xt)[i4];
      s.x += rr.x; s.y += rr.y; s.z += rr.z; s.w += rr.w;
    }
    s.x = fmaxf(s.x, 0.f); s.y = fmaxf(s.y, 0.f);
    s.z = fmaxf(s.z, 0.f); s.w = fmaxf(s.w, 0.f);
    ((float4*)curt)[i4] = s;
    if (final_layer) {
      int idx = i4 * 4;
      int o = idx >> 11, m = idx & 2047;
      outp[(m + 0) * 64 + o] = s.x;
      outp[(m + 1) * 64 + o] = s.y;
      outp[(m + 2) * 64 + o] = s.z;
      outp[(m + 3) * 64 + o] = s.w;
    }
  }
}

extern "C" void kernel_launch(void* const* d_in, const int* in_sizes, int n_in,
                              void* d_out, int out_size, void* d_ws, size_t ws_size,
                              hipStream_t stream) {
  const float* x    = (const float*)d_in[0];  // (2048, 64)
  const float* conn = (const float*)d_in[1];  // (2048, 2048, 12)
  const float* bond = (const float*)d_in[2];  // (2048, 12, 2)
  const float* f0   = (const float*)d_in[3];  // (64, 12, 66)
  const float* f1   = (const float*)d_in[4];
  float* out = (float*)d_out;                 // (2048, 64)

  char* ws = (char*)d_ws;
  float* xt   = (float*)(ws + 0);              // 64x2048 fp32            512 KB
  float* curt = (float*)(ws + 524288);         // 64x2048 fp32            512 KB
  float* bt0  = (float*)(ws + 1048576);        // 64x2048 fp32            512 KB
  float* bt1  = (float*)(ws + 1572864);        // 64x2048 fp32            512 KB
  unsigned short* gtt = (unsigned short*)(ws + 2097152);     // tiled gt    3 MB
  float* part = (float*)(ws + 5242880);        // 16 x 64x2048 fp32        8 MB
  unsigned short* connt = (unsigned short*)(ws + 33554432);  // tiled conn  96 MB

  k_pre<<<6688, 256, 0, stream>>>(x, xt, bond, f0, f1, bt0, bt1, conn, connt);

  for (int layer = 0; layer < 4; ++layer) {
    const float* filt = (layer < 2) ? f0 : f1;
    const float* bt   = (layer < 2) ? bt0 : bt1;
    const float* vin  = (layer == 0) ? xt : curt;
    k_g<<<dim3(4, 64), 256, 0, stream>>>(vin, filt, gtt);
    k_big<<<dim3(32, NSPLIT), 256, 0, stream>>>(connt, gtt, part);
    k_red<<<256, 256, 0, stream>>>(part, bt, xt, curt, out, layer & 1, layer == 3);
  }
}